// Round 4
// baseline (172.696 us; speedup 1.0000x reference)
//
#include <hip/hip_runtime.h>

// ---------------------------------------------------------------------------
// SSIM R6 = R5 (barrier-free single-wave tiles) + masking fix.
// R5 failed (absmax 0.044): ncols = OWIDTH-c0 instead of min(58, OWIDTH-c0),
// so non-last col tiles emitted 64 cols instead of 58 -> 6 double-counted
// cols per boundary AND unmasked outputs whose windows read stat cols 64..69
// (garbage from the next stat row; one read past the LDS array).
// R6 fixes ncols, pads LDS (+5 float4) so the unconditional q[13] read stays
// in-bounds, and fences the LDS read->overwrite transition with
// s_waitcnt lgkmcnt(0) + sched_barrier as same-wave-ordering insurance.
//
// Structure (unchanged from R5):
//  * 1 wave / workgroup, private 8.4 KB LDS. Producer == consumer wave ->
//    zero __syncthreads. Latency hidden by TLP (16 wg/CU, decorrelated).
//  * tile = 64 out rows x 58 out cols; 7 col-tiles x 6 row-strips x 128
//    images = 5376 waves. Last strip y0=314, masks first 6 rows.
//  * stats AoS float4, 1 ds_write_b128/row/col. Horizontal lane (r=t>>3,
//    k=t&7) slides 8 outputs from 14 ds_read_b128. Pitch 65 float4 ->
//    bank quad = (r+j)&7, conflict-free (8-pass minimum).
//  * 8-slot register ring, all indices compile-time static.
//  * SSIM math / summation tree bit-identical to R4 (passed, absmax 0.0).
// Predicted: pass; ssim_main ~24-30 us, VALUBusy ~45%, conflicts ~0.
// ---------------------------------------------------------------------------

#define H 384
#define W 384
#define IMGSZ (H * W)
#define OWIDTH 378
#define NIMG 128
#define NCT 7               // col tiles (58 outputs each; last uses 30)
#define NRS 6               // row strips (64 out rows; last masks first 6)
#define WPI (NCT * NRS)     // 42 waves per image
#define NBLK (NIMG * WPI)   // 5376 partials
#define P4 65               // LDS pitch in float4: quad=(r+j)&7 -> conflict-free
#define CH 8                // chunk rows

__device__ __forceinline__ float wave_reduce(float v) {
#pragma unroll
    for (int off = 32; off > 0; off >>= 1) v += __shfl_down(v, off, 64);
    return v;
}

// Ring slot SN <- new row (XN,YN); retire slot SO; write stat row LR.
// All indices compile-time constants.
#define VST(SN, SO, LR, XN, YN) do {                                      \
    const float xo = xv[SO], yo = yv[SO];                                 \
    const float xn = (XN), yn = (YN);                                     \
    sx += xn - xo; sy += yn - yo;                                         \
    sq = fmaf(xn, xn, fmaf(yn, yn, fmaf(-xo, xo, fmaf(-yo, yo, sq))));    \
    sxy = fmaf(xn, yn, fmaf(-xo, yo, sxy));                               \
    xv[SN] = xn; yv[SN] = yn;                                             \
    st[(LR) * P4 + t] = make_float4(sx, sy, sq, sxy);                     \
} while (0)

__global__ __launch_bounds__(64, 4) void ssim_main(const float* __restrict__ pred,
                                                   const float* __restrict__ act,
                                                   float* __restrict__ partials) {
    __shared__ __align__(16) float4 st[CH * P4 + 5];   // +5: q[13]@r=7,k=7 in-bounds

    const int t = threadIdx.x;          // 0..63, == lane
    const int wid = blockIdx.x;
    const int img = wid / WPI;
    const int rem = wid - img * WPI;
    const int rs = rem / NCT;
    const int ct = rem - rs * NCT;

    const int c0 = ct * 58;
    const bool last_rs = (rs == NRS - 1);
    const int y0 = last_rs ? (H - 70) : rs * 64;   // 314 : 64*rs  (70 input rows)
    const int ylo = last_rs ? 6 : 0;               // rows already done by strip 4
    const int nc_raw = OWIDTH - c0;
    const int ncols = (nc_raw < 58) ? nc_raw : 58; // <-- R6 fix (was OWIDTH-c0)

    int col = c0 + t;
    col = (col < W) ? col : (W - 1);               // clamp: loads valid; outputs masked
    const float* px = pred + (size_t)img * IMGSZ + (size_t)y0 * W + col;
    const float* py = act  + (size_t)img * IMGSZ + (size_t)y0 * W + col;

    // ---------------- prologue: rows 0..13 -> stat rows 0..7 (chunk 0) --------
    float xv[8], yv[8];
    float pfx[7], pfy[7];
#pragma unroll
    for (int i = 0; i < 7; ++i) { xv[i] = px[i * W]; yv[i] = py[i * W]; }
#pragma unroll
    for (int i = 0; i < 7; ++i) { pfx[i] = px[(7 + i) * W]; pfy[i] = py[(7 + i) * W]; }
    float sx = 0.f, sy = 0.f, sq = 0.f, sxy = 0.f;
#pragma unroll
    for (int i = 0; i < 7; ++i) {
        sx += xv[i]; sy += yv[i];
        sq = fmaf(xv[i], xv[i], fmaf(yv[i], yv[i], sq));
        sxy = fmaf(xv[i], yv[i], sxy);
    }
    st[t] = make_float4(sx, sy, sq, sxy);          // stat row 0
    VST(7, 0, 1, pfx[0], pfy[0]);                  // rows 7..13 -> stat rows 1..7
    VST(0, 1, 2, pfx[1], pfy[1]);
    VST(1, 2, 3, pfx[2], pfy[2]);
    VST(2, 3, 4, pfx[3], pfy[3]);
    VST(3, 4, 5, pfx[4], pfy[4]);
    VST(4, 5, 6, pfx[5], pfy[5]);
    VST(5, 6, 7, pfx[6], pfy[6]);
    // ring: rows 7..13 in slots 7,0,1,2,3,4,5; slot 6 stale (row 6)

    // ---------------- chunk loop ----------------
    const int r = t >> 3;                 // stat row 0..7
    const int k = t & 7;                  // col group -> outputs 8k..8k+7
    const int nmax = ncols - 8 * k;       // may be <= 0 (fully masked lane)
    const float4* qbase = st + r * P4 + 8 * k;
    const float C1B = 0.2401f;            // C1 * 49^2
    const float C2B = 2.1168f;            // C2 * 48*49
    float acc = 0.f;

    for (int c = 0; c < 8; ++c) {
        // prefetch next chunk's 8 input rows (consumed after horizontal)
        float nfx[8], nfy[8];
        if (c < 7) {
#pragma unroll
            for (int i = 0; i < 8; ++i) {
                nfx[i] = px[(8 * c + 14 + i) * W];
                nfy[i] = py[(8 * c + 14 + i) * W];
            }
        }
        // ---- horizontal on stat rows 0..7 (out rows y0+8c .. y0+8c+7) ----
        float4 q[14];
#pragma unroll
        for (int j = 0; j < 14; ++j) q[j] = qbase[j];
        float Sx  = ((q[0].x + q[1].x) + (q[2].x + q[3].x)) + ((q[4].x + q[5].x) + q[6].x);
        float Sy  = ((q[0].y + q[1].y) + (q[2].y + q[3].y)) + ((q[4].y + q[5].y) + q[6].y);
        float Sq  = ((q[0].z + q[1].z) + (q[2].z + q[3].z)) + ((q[4].z + q[5].z) + q[6].z);
        float Sxy = ((q[0].w + q[1].w) + (q[2].w + q[3].w)) + ((q[4].w + q[5].w) + q[6].w);
        const bool rowok = (8 * c + r) >= ylo;
#pragma unroll
        for (int j = 0; j < 8; ++j) {
            if (j) {
                Sx  += q[j + 6].x - q[j - 1].x;
                Sy  += q[j + 6].y - q[j - 1].y;
                Sq  += q[j + 6].z - q[j - 1].z;
                Sxy += q[j + 6].w - q[j - 1].w;
            }
            const float p  = Sx * Sy;
            const float qq = fmaf(Sx, Sx, Sy * Sy);
            const float n1 = fmaf(2.f, p, C1B);
            const float n2 = fmaf(98.f, Sxy, fmaf(-2.f, p, C2B));
            const float d1 = qq + C1B;
            const float d2 = fmaf(49.f, Sq, C2B - qq);
            const float s  = (n1 * n2) * __builtin_amdgcn_rcpf(d1 * d2);
            acc = (rowok && (j < nmax)) ? acc + s : acc;   // select (garbage may be NaN)
        }
        // pin: all ds_reads above are issued+drained before the overwrites below
        __builtin_amdgcn_sched_barrier(0);
        asm volatile("s_waitcnt lgkmcnt(0)" ::: "memory");
        __builtin_amdgcn_sched_barrier(0);
        if (c < 7) {
            VST(6, 7, 0, nfx[0], nfy[0]);   // rows 8c+14..8c+21 -> stat rows 0..7
            VST(7, 0, 1, nfx[1], nfy[1]);
            VST(0, 1, 2, nfx[2], nfy[2]);
            VST(1, 2, 3, nfx[3], nfy[3]);
            VST(2, 3, 4, nfx[4], nfy[4]);
            VST(3, 4, 5, nfx[5], nfy[5]);
            VST(4, 5, 6, nfx[6], nfy[6]);
            VST(5, 6, 7, nfx[7], nfy[7]);
            __builtin_amdgcn_sched_barrier(0);  // writes stay before next chunk's reads
        }
    }

    // ---------------- per-wave partial ----------------
    const float wsum = wave_reduce(acc);
    if (t == 0) partials[wid] = wsum;
}

__global__ __launch_bounds__(1024) void ssim_finalize(const float* __restrict__ partials,
                                                      float* __restrict__ out) {
    __shared__ double red[1024];
    const int t = threadIdx.x;
    double s = 0.0;
    for (int i = t; i < NBLK; i += 1024) s += (double)partials[i];
    red[t] = s;
    __syncthreads();
#pragma unroll
    for (int off = 512; off > 0; off >>= 1) {
        if (t < off) red[t] += red[t + off];
        __syncthreads();
    }
    if (t == 0) out[0] = (float)(red[0] / ((double)NIMG * OWIDTH * OWIDTH));
}

extern "C" void kernel_launch(void* const* d_in, const int* in_sizes, int n_in,
                              void* d_out, int out_size, void* d_ws, size_t ws_size,
                              hipStream_t stream) {
    const float* pred = (const float*)d_in[0];
    const float* act  = (const float*)d_in[1];
    float* partials = (float*)d_ws;          // NBLK floats, fully overwritten each call
    ssim_main<<<NBLK, 64, 0, stream>>>(pred, act, partials);
    ssim_finalize<<<1, 1024, 0, stream>>>(partials, (float*)d_out);
}